// Round 4
// baseline (100.248 us; speedup 1.0000x reference)
//
#include <hip/hip_runtime.h>
#include <math.h>

// KF filtered-position windowed loss, collapsed scalar-recurrence form.
// loss = mean_{b, t in [1,T), d} ( kp_t*(z_t - v) + dt*(v - w_t) )^2,
// v <- v + kv_t*(z_t - v), v0 = 0; gains from the batch-independent scalar
// Riccati recursion (q_pos and p0 provably cancel).
//
// Round 4: revert to R2's direct-strided-load structure (best measured);
// inputs are L3-resident (33.5 MB < 256 MB, harness restore keeps them warm)
// so coalescing is secondary — occupancy/latency is the lever. Lc 16 -> 8
// doubles TLP to 4 waves/SIMD and shortens the serial chain to 20 steps;
// z-read amplification 2.5x is absorbed by L3. Wc=12 warm-up unchanged
// (state contraction ~0.73 -> ~1e-8 loss error vs 7.7e-7 threshold).

namespace {
constexpr int   Tn = 4096;
constexpr float DTc = 0.005f;
constexpr int   Lc = 8;             // chunk emit length
constexpr int   Wc = 12;            // warm-up length
constexpr int   NCHUNK = Tn / Lc;   // 512
constexpr int   NTRANS_C = 8;       // chunks with t0 < 64 use exact gains
constexpr int   GAINS_N = 64;
constexpr float INVC = 1.0f / (512.0f * 4095.0f * 2.0f);
}

__global__ __launch_bounds__(256) void kf_loss_kernel(
    const float* __restrict__ pred,
    const float* __restrict__ targ,
    const float* __restrict__ q_vel,
    const float* __restrict__ r_vel,
    float* __restrict__ out)
{
  const int b = ((blockIdx.x & 1) << 8) + threadIdx.x;  // 0..511
  const int c = blockIdx.x >> 1;                        // 0..511
  const int t0 = c * Lc;

  const float qv = q_vel[0];
  const float r  = r_vel[0];

  const float4* z4 = (const float4*)(pred + (size_t)b * (Tn * 2));
  const float4* w4 = (const float4*)(targ + (size_t)b * (Tn * 2));

  float acc = 0.0f;
  __shared__ float skp[GAINS_N];
  __shared__ float skv[GAINS_N];

  if (c >= NTRANS_C) {
    // ---- steady-state gains, closed form (Riccati fixed point)
    float u   = 0.5f * (qv + sqrtf(fmaf(qv, qv, 4.0f * qv * r)));
    float inv = 1.0f / (u + r);
    float kv  = u * inv;
    float cst = u - qv;
    float bst = (DTc * cst * r) / u;
    float kp  = (bst + DTc * cst) * inv;

    float vx = 0.0f, vy = 0.0f;
    int j = (t0 - Wc) >> 1;          // float4 index = timestep/2
    #pragma unroll
    for (int i = 0; i < Wc / 2; ++i, ++j) {
      float4 z = z4[j];
      vx = fmaf(kv, z.x - vx, vx);  vy = fmaf(kv, z.y - vy, vy);
      vx = fmaf(kv, z.z - vx, vx);  vy = fmaf(kv, z.w - vy, vy);
    }
    #pragma unroll
    for (int i = 0; i < Lc / 2; ++i, ++j) {
      float4 z = z4[j];
      float4 w = w4[j];
      float ix = z.x - vx, iy = z.y - vy;
      float ex = fmaf(kp, ix, DTc * (vx - w.x));
      float ey = fmaf(kp, iy, DTc * (vy - w.y));
      acc = fmaf(ex, ex, acc);  acc = fmaf(ey, ey, acc);
      vx = fmaf(kv, ix, vx);    vy = fmaf(kv, iy, vy);
      ix = z.z - vx;            iy = z.w - vy;
      ex = fmaf(kp, ix, DTc * (vx - w.z));
      ey = fmaf(kp, iy, DTc * (vy - w.w));
      acc = fmaf(ex, ex, acc);  acc = fmaf(ey, ey, acc);
      vx = fmaf(kv, ix, vx);    vy = fmaf(kv, iy, vy);
    }
  } else {
    // ---- transient chunks (t0 < 64): exact Riccati gain sequence in LDS
    if (threadIdx.x == 0) {
      float bcov = 0.0f, ccov = 1.0f;   // P0 = I -> b=0, c=1
      for (int t = 0; t < GAINS_N; ++t) {
        float bp = fmaf(DTc, ccov, bcov);
        float cp = ccov + qv;
        float inv = 1.0f / (cp + r);
        float kp = bp * inv;
        float kv = cp * inv;
        skp[t] = kp;  skv[t] = kv;
        bcov = fmaf(-kp, cp, bp);
        ccov = fmaf(-kv, cp, cp);
      }
    }
    __syncthreads();

    const float2* z2 = (const float2*)z4;
    const float2* w2 = (const float2*)w4;
    float vx = 0.0f, vy = 0.0f;
    int t = t0 - Wc;  if (t < 0) t = 0;
    for (; t < t0; ++t) {
      float2 z = z2[t];
      float kvt = skv[t];
      vx = fmaf(kvt, z.x - vx, vx);  vy = fmaf(kvt, z.y - vy, vy);
    }
    for (; t < t0 + Lc; ++t) {
      float2 z = z2[t];
      float ix = z.x - vx, iy = z.y - vy;
      if (t > 0) {
        float2 w = w2[t];
        float kpt = skp[t];
        float ex = fmaf(kpt, ix, DTc * (vx - w.x));
        float ey = fmaf(kpt, iy, DTc * (vy - w.y));
        acc = fmaf(ex, ex, acc);  acc = fmaf(ey, ey, acc);
      }
      float kvt = skv[t];
      vx = fmaf(kvt, ix, vx);  vy = fmaf(kvt, iy, vy);
    }
  }

  // ---- block reduction (4 waves), one scaled atomic per block
  #pragma unroll
  for (int off = 32; off > 0; off >>= 1)
    acc += __shfl_down(acc, off);
  __shared__ float wpart[4];
  const int lane = threadIdx.x & 63, wid = threadIdx.x >> 6;
  if (lane == 0) wpart[wid] = acc;
  __syncthreads();
  if (threadIdx.x == 0) {
    float s = (wpart[0] + wpart[1]) + (wpart[2] + wpart[3]);
    atomicAdd(out, s * INVC);
  }
}

extern "C" void kernel_launch(void* const* d_in, const int* in_sizes, int n_in,
                              void* d_out, int out_size, void* d_ws, size_t ws_size,
                              hipStream_t stream) {
  // inputs: 0 pred_vel (B,T,2) f32, 1 targ_vel (B,T,2) f32,
  //         2 q_pos (unused), 3 q_vel, 4 r_vel, 5 p0 (unused)
  const float* pred = (const float*)d_in[0];
  const float* targ = (const float*)d_in[1];
  const float* qv   = (const float*)d_in[3];
  const float* rv   = (const float*)d_in[4];
  float* out = (float*)d_out;

  hipMemsetAsync(out, 0, sizeof(float), stream);  // d_out is poisoned 0xAA

  dim3 grid(NCHUNK * 2);   // 1024 blocks: (chunk, batch-half)
  dim3 block(256);
  kf_loss_kernel<<<grid, block, 0, stream>>>(pred, targ, qv, rv, out);
}

// Round 5
// 90.527 us; speedup vs baseline: 1.1074x; 1.1074x over previous
//
#include <hip/hip_runtime.h>
#include <math.h>

// KF filtered-position windowed loss, collapsed scalar-recurrence form.
// loss = mean_{b, t in [1,T), d} ( kp_t*(z_t - v) + dt*(v - w_t) )^2,
// v <- v + kv_t*(z_t - v), v0 = 0; gains from the batch-independent scalar
// Riccati recursion (q_pos and p0 provably cancel).
//
// Round 5 = Round 2 verbatim (best measured: 90.1 us). Lc=16/Wc=12 chunking,
// direct strided float4 loads, 512 blocks (2 waves/SIMD), 1.75x z-read
// amplification -> 46 MB HBM traffic ~ 7.3 us BW floor. R3 (LDS staging) and
// R4 (Lc=8, 2.5x amp) both regressed ~9 us: the harness's 268 MB ws-poison
// evicts L3 every iteration, so inputs come from HBM and amplification is
// the real cost; extra sync/addressing machinery doesn't pay.

namespace {
constexpr int   Tn = 4096;
constexpr float DTc = 0.005f;
constexpr int   Lc = 16;            // chunk emit length
constexpr int   Wc = 12;            // warm-up length
constexpr int   NCHUNK = Tn / Lc;   // 256
constexpr int   NTRANS_C = 4;       // chunks with t0 < 64 use exact gains
constexpr int   GAINS_N = 64;
constexpr float INVC = 1.0f / (512.0f * 4095.0f * 2.0f);
}

__global__ __launch_bounds__(256) void kf_loss_kernel(
    const float* __restrict__ pred,
    const float* __restrict__ targ,
    const float* __restrict__ q_vel,
    const float* __restrict__ r_vel,
    float* __restrict__ out)
{
  const int b = ((blockIdx.x & 1) << 8) + threadIdx.x;  // 0..511
  const int c = blockIdx.x >> 1;                        // 0..255
  const int t0 = c * Lc;

  const float qv = q_vel[0];
  const float r  = r_vel[0];

  const float4* z4 = (const float4*)(pred + (size_t)b * (Tn * 2));
  const float4* w4 = (const float4*)(targ + (size_t)b * (Tn * 2));

  float acc = 0.0f;
  __shared__ float skp[GAINS_N];
  __shared__ float skv[GAINS_N];

  if (c >= NTRANS_C) {
    // ---- steady-state gains, closed form (Riccati fixed point)
    float u   = 0.5f * (qv + sqrtf(fmaf(qv, qv, 4.0f * qv * r)));
    float inv = 1.0f / (u + r);
    float kv  = u * inv;
    float cst = u - qv;
    float bst = (DTc * cst * r) / u;
    float kp  = (bst + DTc * cst) * inv;

    float vx = 0.0f, vy = 0.0f;
    int j = (t0 - Wc) >> 1;          // float4 index = timestep/2
    #pragma unroll
    for (int i = 0; i < Wc / 2; ++i, ++j) {
      float4 z = z4[j];
      vx = fmaf(kv, z.x - vx, vx);  vy = fmaf(kv, z.y - vy, vy);
      vx = fmaf(kv, z.z - vx, vx);  vy = fmaf(kv, z.w - vy, vy);
    }
    #pragma unroll
    for (int i = 0; i < Lc / 2; ++i, ++j) {
      float4 z = z4[j];
      float4 w = w4[j];
      float ix = z.x - vx, iy = z.y - vy;
      float ex = fmaf(kp, ix, DTc * (vx - w.x));
      float ey = fmaf(kp, iy, DTc * (vy - w.y));
      acc = fmaf(ex, ex, acc);  acc = fmaf(ey, ey, acc);
      vx = fmaf(kv, ix, vx);    vy = fmaf(kv, iy, vy);
      ix = z.z - vx;            iy = z.w - vy;
      ex = fmaf(kp, ix, DTc * (vx - w.z));
      ey = fmaf(kp, iy, DTc * (vy - w.w));
      acc = fmaf(ex, ex, acc);  acc = fmaf(ey, ey, acc);
      vx = fmaf(kv, ix, vx);    vy = fmaf(kv, iy, vy);
    }
  } else {
    // ---- transient chunks (t0 < 64): exact Riccati gain sequence in LDS
    if (threadIdx.x == 0) {
      float bcov = 0.0f, ccov = 1.0f;   // P0 = I -> b=0, c=1
      for (int t = 0; t < GAINS_N; ++t) {
        float bp = fmaf(DTc, ccov, bcov);
        float cp = ccov + qv;
        float inv = 1.0f / (cp + r);
        float kp = bp * inv;
        float kv = cp * inv;
        skp[t] = kp;  skv[t] = kv;
        bcov = fmaf(-kp, cp, bp);
        ccov = fmaf(-kv, cp, cp);
      }
    }
    __syncthreads();

    const float2* z2 = (const float2*)z4;
    const float2* w2 = (const float2*)w4;
    float vx = 0.0f, vy = 0.0f;
    int t = t0 - Wc;  if (t < 0) t = 0;
    for (; t < t0; ++t) {
      float2 z = z2[t];
      float kvt = skv[t];
      vx = fmaf(kvt, z.x - vx, vx);  vy = fmaf(kvt, z.y - vy, vy);
    }
    for (; t < t0 + Lc; ++t) {
      float2 z = z2[t];
      float ix = z.x - vx, iy = z.y - vy;
      if (t > 0) {
        float2 w = w2[t];
        float kpt = skp[t];
        float ex = fmaf(kpt, ix, DTc * (vx - w.x));
        float ey = fmaf(kpt, iy, DTc * (vy - w.y));
        acc = fmaf(ex, ex, acc);  acc = fmaf(ey, ey, acc);
      }
      float kvt = skv[t];
      vx = fmaf(kvt, ix, vx);  vy = fmaf(kvt, iy, vy);
    }
  }

  // ---- block reduction (4 waves), one scaled atomic per block
  #pragma unroll
  for (int off = 32; off > 0; off >>= 1)
    acc += __shfl_down(acc, off);
  __shared__ float wpart[4];
  const int lane = threadIdx.x & 63, wid = threadIdx.x >> 6;
  if (lane == 0) wpart[wid] = acc;
  __syncthreads();
  if (threadIdx.x == 0) {
    float s = (wpart[0] + wpart[1]) + (wpart[2] + wpart[3]);
    atomicAdd(out, s * INVC);
  }
}

extern "C" void kernel_launch(void* const* d_in, const int* in_sizes, int n_in,
                              void* d_out, int out_size, void* d_ws, size_t ws_size,
                              hipStream_t stream) {
  // inputs: 0 pred_vel (B,T,2) f32, 1 targ_vel (B,T,2) f32,
  //         2 q_pos (unused), 3 q_vel, 4 r_vel, 5 p0 (unused)
  const float* pred = (const float*)d_in[0];
  const float* targ = (const float*)d_in[1];
  const float* qv   = (const float*)d_in[3];
  const float* rv   = (const float*)d_in[4];
  float* out = (float*)d_out;

  hipMemsetAsync(out, 0, sizeof(float), stream);  // d_out is poisoned 0xAA

  dim3 grid(NCHUNK * 2);   // 512 blocks: (chunk, batch-half)
  dim3 block(256);
  kf_loss_kernel<<<grid, block, 0, stream>>>(pred, targ, qv, rv, out);
}